// Round 10
// baseline (4996.252 us; speedup 1.0000x reference)
//
#include <hip/hip_runtime.h>
#include <math.h>

#define DIM 128
#define E_NUM 100000
#define P_NUM 800000
#define G_NUM 1000
#define T_STEPS 8
#define R_UNITS 256

typedef __attribute__((ext_vector_type(8))) short bf16x8;   // 8 bf16 = 4 VGPRs
typedef __attribute__((ext_vector_type(4))) float f32x4;    // 16x16 MFMA acc

typedef unsigned short ushort_t;
typedef unsigned int   uint_t;

__device__ __forceinline__ float selu_f(float x) {
    const float alpha = 1.6732632423543772f;
    const float scale = 1.0507009873554805f;
    return x > 0.f ? scale * x : scale * alpha * expm1f(x);
}

__device__ __forceinline__ ushort_t f2bf(float x) {
    uint_t u = __float_as_uint(x);
    uint_t r = (u + 0x7fffu + ((u >> 16) & 1u)) >> 16;
    return (ushort_t)r;
}
__device__ __forceinline__ float bf2f(ushort_t h) {
    return __uint_as_float(((uint_t)h) << 16);
}

// ===========================================================================
// CSR build (once per launch). Multi-block scan.
// ===========================================================================
__global__ __launch_bounds__(256)
void hist_kernel(const int* __restrict__ second, int* __restrict__ counts)
{
    const int p = blockIdx.x * 256 + threadIdx.x;
    atomicAdd(&counts[second[p]], 1);
}

__global__ __launch_bounds__(1024)
void scanA_kernel(const int* __restrict__ counts, int* __restrict__ offsets,
                  int* __restrict__ bsum)
{
    __shared__ int buf[1024];
    const int i = blockIdx.x * 1024 + threadIdx.x;
    const int v = (i < E_NUM) ? counts[i] : 0;
    buf[threadIdx.x] = v;
    __syncthreads();
    for (int off = 1; off < 1024; off <<= 1) {
        const int t = (threadIdx.x >= off) ? buf[threadIdx.x - off] : 0;
        __syncthreads();
        buf[threadIdx.x] += t;
        __syncthreads();
    }
    if (i < E_NUM) offsets[i] = buf[threadIdx.x] - v;   // block-local exclusive
    if (threadIdx.x == 1023) bsum[blockIdx.x] = buf[1023];
}

__global__ void scanB_kernel(int* __restrict__ bsum, int* __restrict__ offsets)
{
    int acc = 0;
    for (int b = 0; b < 98; b++) { const int t = bsum[b]; bsum[b] = acc; acc += t; }
    offsets[E_NUM] = P_NUM;
}

__global__ __launch_bounds__(1024)
void scanC_kernel(int* __restrict__ offsets, const int* __restrict__ bsum)
{
    const int i = blockIdx.x * 1024 + threadIdx.x;
    if (i < E_NUM) offsets[i] += bsum[blockIdx.x];
}

__global__ __launch_bounds__(256)
void fill_kernel(const int* __restrict__ first, const int* __restrict__ second,
                 const int* __restrict__ offsets, int* __restrict__ cursor,
                 int* __restrict__ sfirst, int* __restrict__ ssecond)
{
    const int p = blockIdx.x * 256 + threadIdx.x;
    const int d = second[p];
    const int pos = atomicAdd(&cursor[d], 1);
    const int idx = offsets[d] + pos;
    sfirst[idx] = first[p];
    ssecond[idx] = d;
}

// ===========================================================================
// One-time prep (same as R8/R9).
// ===========================================================================
__global__ __launch_bounds__(256)
void cast_h_kernel(const float* __restrict__ src,
                   ushort_t* __restrict__ dhi, ushort_t* __restrict__ dlo)
{
    const int idx = blockIdx.x * 256 + threadIdx.x;
    const float x = src[idx];
    const ushort_t hi = f2bf(x);
    dhi[idx] = hi;
    dlo[idx] = f2bf(x - bf2f(hi));
}

__global__ __launch_bounds__(256)
void wsplit_build_kernel(const float* __restrict__ Wmsg,
                         ushort_t* __restrict__ wt, ushort_t* __restrict__ wy)
{
    const int idx  = blockIdx.x * 256 + threadIdx.x;   // 8192 slots (2 halves)
    const int lane = idx & 63;
    const int nt   = (idx >> 6) & 7;
    const int comp = (idx >> 9) & 1;
    const int ks   = (idx >> 10) & 3;
    const int half = idx >> 12;
    const int n    = nt * 16 + (lane & 15);
    const int kb   = ks * 32 + (lane >> 4) * 8 + half * 128;
    ushort_t* dst  = half ? wy : wt;
    const int slot = idx & 4095;
#pragma unroll
    for (int j = 0; j < 8; j++) {
        const float w = Wmsg[(size_t)(kb + j) * DIM + n];
        const ushort_t hi = f2bf(w);
        dst[(size_t)slot * 8 + j] = comp ? f2bf(w - bf2f(hi)) : hi;
    }
}

__global__ __launch_bounds__(256)
void wb_build_kernel(const float* __restrict__ K, const float* __restrict__ U,
                     ushort_t* __restrict__ wb)
{
    const int idx  = blockIdx.x * 256 + threadIdx.x;   // 24576 slots
    const int lane = idx & 63;
    int t = idx >> 6;
    const int nt   = t % 24;  t /= 24;
    const int comp = t & 1;   t >>= 1;
    const int gemm = t & 1;
    const int ks   = t >> 1;
    const float* src = gemm ? U : K;
    const int n  = nt * 16 + (lane & 15);
    const int kb = ks * 32 + (lane >> 4) * 8;
#pragma unroll
    for (int j = 0; j < 8; j++) {
        const float w = src[(size_t)(kb + j) * 384 + n];
        const ushort_t hi = f2bf(w);
        wb[(size_t)idx * 8 + j] = comp ? f2bf(w - bf2f(hi)) : hi;
    }
}

// ===========================================================================
// Y2 kernel: Y2 = h @ W_bot  [E x 128] (same as R8).
// ===========================================================================
__global__ __launch_bounds__(256, 4)
void y2_kernel(const ushort_t* __restrict__ hbh, const ushort_t* __restrict__ hbl,
               const ushort_t* __restrict__ wy, float* __restrict__ Y2)
{
    const int tid  = threadIdx.x;
    const int lane = tid & 63;
    const int w    = tid >> 6;
    const int e0   = blockIdx.x * 32;
    const int m16  = lane & 15;
    const int quad = lane >> 4;

    f32x4 acc[2][2] = {};
#pragma unroll
    for (int ks = 0; ks < 4; ks++) {
        const int koff = ks * 32 + quad * 8;
        bf16x8 ah[2], al[2];
#pragma unroll
        for (int rt = 0; rt < 2; rt++) {
            const size_t row = (size_t)(e0 + rt * 16 + m16);
            ah[rt] = *(const bf16x8*)(hbh + row * DIM + koff);
            al[rt] = *(const bf16x8*)(hbl + row * DIM + koff);
        }
#pragma unroll
        for (int ntl = 0; ntl < 2; ntl++) {
            const int nt = w * 2 + ntl;
            const bf16x8 bh = *(const bf16x8*)(wy + (size_t)(((ks * 2 + 0) * 8 + nt) * 64 + lane) * 8);
            const bf16x8 bl = *(const bf16x8*)(wy + (size_t)(((ks * 2 + 1) * 8 + nt) * 64 + lane) * 8);
#pragma unroll
            for (int rt = 0; rt < 2; rt++) {
                acc[rt][ntl] = __builtin_amdgcn_mfma_f32_16x16x32_bf16(ah[rt], bh, acc[rt][ntl], 0, 0, 0);
                acc[rt][ntl] = __builtin_amdgcn_mfma_f32_16x16x32_bf16(al[rt], bh, acc[rt][ntl], 0, 0, 0);
                acc[rt][ntl] = __builtin_amdgcn_mfma_f32_16x16x32_bf16(ah[rt], bl, acc[rt][ntl], 0, 0, 0);
            }
        }
    }
#pragma unroll
    for (int rt = 0; rt < 2; rt++)
#pragma unroll
        for (int ntl = 0; ntl < 2; ntl++) {
            const int c = (w * 2 + ntl) * 16 + m16;
#pragma unroll
            for (int reg = 0; reg < 4; reg++) {
                const size_t row = (size_t)(e0 + rt * 16 + quad * 4 + reg);
                Y2[row * DIM + c] = acc[rt][ntl][reg];
            }
        }
}

// ===========================================================================
// msg kernel: agg[d] = sum_{p: second[p]=d} selu(h[first_p]@W_top + Y2[d] + b)
// R10: sched_barrier(0) fence between the 16-load A-gather batch and the
// MFMA section — the compiler may NOT sink the gathers to their use sites
// (R9 proved it does: VGPR stayed 60). All 16 misses per wave now in flight
// concurrently (~8x the memory-level parallelism).
// ===========================================================================
__global__ __launch_bounds__(256, 2)
void msg_kernel(const ushort_t* __restrict__ hbh, const ushort_t* __restrict__ hbl,
                const int* __restrict__ sfirst, const int* __restrict__ ssecond,
                const ushort_t* __restrict__ wt, const float* __restrict__ Y2,
                const float* __restrict__ bmsg, float* __restrict__ agg)
{
    __shared__ int f_s[128];
    __shared__ int s_sh[128];

    const int tid  = threadIdx.x;
    const int lane = tid & 63;
    const int w    = tid >> 6;
    const int p0   = blockIdx.x * 128;

    if (tid < 128) {
        f_s[tid]  = sfirst[p0 + tid];
        s_sh[tid] = ssecond[p0 + tid];
    }
    __syncthreads();

    const int m16  = lane & 15;
    const int quad = lane >> 4;
    const int r0   = f_s[w * 32 + m16];
    const int r1   = f_s[w * 32 + 16 + m16];

    // ---- batched A-gather: 16 independent 16B loads ----
    bf16x8 A0h[4], A0l[4], A1h[4], A1l[4];
    {
        const ushort_t* b0 = hbh + (size_t)r0 * DIM;
        const ushort_t* l0 = hbl + (size_t)r0 * DIM;
        const ushort_t* b1 = hbh + (size_t)r1 * DIM;
        const ushort_t* l1 = hbl + (size_t)r1 * DIM;
        const int q8 = quad * 8;
#pragma unroll
        for (int ks = 0; ks < 4; ks++) {
            const int koff = ks * 32 + q8;
            A0h[ks] = *(const bf16x8*)(b0 + koff);
            A0l[ks] = *(const bf16x8*)(l0 + koff);
            A1h[ks] = *(const bf16x8*)(b1 + koff);
            A1l[ks] = *(const bf16x8*)(l1 + koff);
        }
    }
    // FENCE: no instruction may cross — gathers must all issue before the
    // MFMA section's first s_waitcnt. This is the whole point of R10.
    __builtin_amdgcn_sched_barrier(0);

    f32x4 acc[2][8];
#pragma unroll
    for (int rt = 0; rt < 2; rt++)
#pragma unroll
        for (int nt = 0; nt < 8; nt++) acc[rt][nt] = {};

#pragma unroll
    for (int ks = 0; ks < 4; ks++) {
#pragma unroll
        for (int nt = 0; nt < 8; nt++) {
            const bf16x8 bh = *(const bf16x8*)(wt + (size_t)(((ks * 2 + 0) * 8 + nt) * 64 + lane) * 8);
            const bf16x8 bl = *(const bf16x8*)(wt + (size_t)(((ks * 2 + 1) * 8 + nt) * 64 + lane) * 8);
            acc[0][nt] = __builtin_amdgcn_mfma_f32_16x16x32_bf16(A0h[ks], bh, acc[0][nt], 0, 0, 0);
            acc[0][nt] = __builtin_amdgcn_mfma_f32_16x16x32_bf16(A0l[ks], bh, acc[0][nt], 0, 0, 0);
            acc[0][nt] = __builtin_amdgcn_mfma_f32_16x16x32_bf16(A0h[ks], bl, acc[0][nt], 0, 0, 0);
            acc[1][nt] = __builtin_amdgcn_mfma_f32_16x16x32_bf16(A1h[ks], bh, acc[1][nt], 0, 0, 0);
            acc[1][nt] = __builtin_amdgcn_mfma_f32_16x16x32_bf16(A1l[ks], bh, acc[1][nt], 0, 0, 0);
            acc[1][nt] = __builtin_amdgcn_mfma_f32_16x16x32_bf16(A1h[ks], bl, acc[1][nt], 0, 0, 0);
        }
    }

    // ---- transform: val = selu(acc + Y2[dest_row] + bias) ----
    float bb[8];
#pragma unroll
    for (int nt = 0; nt < 8; nt++) bb[nt] = bmsg[nt * 16 + m16];

#pragma unroll
    for (int rt = 0; rt < 2; rt++) {
#pragma unroll
        for (int reg = 0; reg < 4; reg++) {
            const int row_l = w * 32 + rt * 16 + quad * 4 + reg;
            const int d = s_sh[row_l];
            const float* y2row = Y2 + (size_t)d * DIM;
#pragma unroll
            for (int nt = 0; nt < 8; nt++) {
                acc[rt][nt][reg] = selu_f(acc[rt][nt][reg] + y2row[nt * 16 + m16] + bb[nt]);
            }
        }
    }

    // ---- per-run segmented sums over the wave's 32 rows ----
    const int wbase = p0 + w * 32;
    const int s_before = (wbase == 0) ? -1 : ssecond[wbase - 1];
    const int s_after  = (wbase + 32 >= P_NUM) ? -1 : ssecond[wbase + 32];

    int start = 0;
    while (start < 32) {
        const int d = s_sh[w * 32 + start];
        int end = start + 1;
        while (end < 32 && s_sh[w * 32 + end] == d) end++;
        const bool atom = (start == 0 && d == s_before) ||
                          (end == 32 && d == s_after);
#pragma unroll
        for (int nt = 0; nt < 8; nt++) {
            float part = 0.f;
#pragma unroll
            for (int reg = 0; reg < 4; reg++) {
                const int ra = quad * 4 + reg;
                const int rb = 16 + ra;
                part += (ra >= start && ra < end) ? acc[0][nt][reg] : 0.f;
                part += (rb >= start && rb < end) ? acc[1][nt][reg] : 0.f;
            }
            part += __shfl_xor(part, 16, 64);
            part += __shfl_xor(part, 32, 64);
            if (lane < 16) {
                float* dst = agg + (size_t)d * DIM + nt * 16 + lane;
                if (atom) atomicAdd(dst, part);
                else      *dst = part;
            }
        }
        start = end;
    }
}

// ===========================================================================
// GRU kernel, register-gates. R10: per-ks, issue all 16 A-side loads
// (agg x2, hh, hl for 4 row-tiles) then sched_barrier(0) before split/MFMA.
// ===========================================================================
__global__ __launch_bounds__(512, 3)
void gru_kernel(const float* __restrict__ agg,
                ushort_t* __restrict__ hbh, ushort_t* __restrict__ hbl,
                const ushort_t* __restrict__ wb, const float* __restrict__ bias)
{
    const int tid  = threadIdx.x;
    const int lane = tid & 63;
    const int w    = tid >> 6;          // 0..7
    const int e0   = blockIdx.x * 64;
    const int m16  = lane & 15;
    const int quad = lane >> 4;

    f32x4 az[4] = {}, ar[4] = {}, ahx[4] = {}, ahh[4] = {};

#define WB(ks_, gm_, cp_, nt_) \
    (*(const bf16x8*)(wb + ((size_t)(((ks_) * 96) + (gm_) * 48 + (cp_) * 24 + (nt_)) * 64 + lane) * 8))

#pragma unroll
    for (int ks = 0; ks < 4; ks++) {
        const int koff = ks * 32 + quad * 8;

        // ---- batched loads for all 4 row-tiles ----
        float4 v0[4], v1[4];
        bf16x8 hh[4], hl[4];
#pragma unroll
        for (int rt = 0; rt < 4; rt++) {
            int row = e0 + rt * 16 + m16;
            if (row >= E_NUM) row = E_NUM - 1;
            const float* xp = agg + (size_t)row * DIM + koff;
            v0[rt] = *(const float4*)xp;
            v1[rt] = *(const float4*)(xp + 4);
            hh[rt] = *(const bf16x8*)(hbh + (size_t)row * DIM + koff);
            hl[rt] = *(const bf16x8*)(hbl + (size_t)row * DIM + koff);
        }
        __builtin_amdgcn_sched_barrier(0);

        const bf16x8 KzH = WB(ks, 0, 0, w),      KzL = WB(ks, 0, 1, w);
        const bf16x8 UzH = WB(ks, 1, 0, w),      UzL = WB(ks, 1, 1, w);
        const bf16x8 KrH = WB(ks, 0, 0, w + 8),  KrL = WB(ks, 0, 1, w + 8);
        const bf16x8 UrH = WB(ks, 1, 0, w + 8),  UrL = WB(ks, 1, 1, w + 8);
        const bf16x8 KhH = WB(ks, 0, 0, w + 16), KhL = WB(ks, 0, 1, w + 16);
        const bf16x8 UhH = WB(ks, 1, 0, w + 16), UhL = WB(ks, 1, 1, w + 16);

#pragma unroll
        for (int rt = 0; rt < 4; rt++) {
            const float xv[8] = {v0[rt].x, v0[rt].y, v0[rt].z, v0[rt].w,
                                 v1[rt].x, v1[rt].y, v1[rt].z, v1[rt].w};
            bf16x8 xh, xl;
#pragma unroll
            for (int j = 0; j < 8; j++) {
                const ushort_t hi = f2bf(xv[j]);
                xh[j] = (short)hi;
                xl[j] = (short)f2bf(xv[j] - bf2f(hi));
            }

            az[rt] = __builtin_amdgcn_mfma_f32_16x16x32_bf16(xh, KzH, az[rt], 0, 0, 0);
            az[rt] = __builtin_amdgcn_mfma_f32_16x16x32_bf16(xl, KzH, az[rt], 0, 0, 0);
            az[rt] = __builtin_amdgcn_mfma_f32_16x16x32_bf16(xh, KzL, az[rt], 0, 0, 0);
            az[rt] = __builtin_amdgcn_mfma_f32_16x16x32_bf16(hh[rt], UzH, az[rt], 0, 0, 0);
            az[rt] = __builtin_amdgcn_mfma_f32_16x16x32_bf16(hl[rt], UzH, az[rt], 0, 0, 0);
            az[rt] = __builtin_amdgcn_mfma_f32_16x16x32_bf16(hh[rt], UzL, az[rt], 0, 0, 0);

            ar[rt] = __builtin_amdgcn_mfma_f32_16x16x32_bf16(xh, KrH, ar[rt], 0, 0, 0);
            ar[rt] = __builtin_amdgcn_mfma_f32_16x16x32_bf16(xl, KrH, ar[rt], 0, 0, 0);
            ar[rt] = __builtin_amdgcn_mfma_f32_16x16x32_bf16(xh, KrL, ar[rt], 0, 0, 0);
            ar[rt] = __builtin_amdgcn_mfma_f32_16x16x32_bf16(hh[rt], UrH, ar[rt], 0, 0, 0);
            ar[rt] = __builtin_amdgcn_mfma_f32_16x16x32_bf16(hl[rt], UrH, ar[rt], 0, 0, 0);
            ar[rt] = __builtin_amdgcn_mfma_f32_16x16x32_bf16(hh[rt], UrL, ar[rt], 0, 0, 0);

            ahx[rt] = __builtin_amdgcn_mfma_f32_16x16x32_bf16(xh, KhH, ahx[rt], 0, 0, 0);
            ahx[rt] = __builtin_amdgcn_mfma_f32_16x16x32_bf16(xl, KhH, ahx[rt], 0, 0, 0);
            ahx[rt] = __builtin_amdgcn_mfma_f32_16x16x32_bf16(xh, KhL, ahx[rt], 0, 0, 0);
            ahh[rt] = __builtin_amdgcn_mfma_f32_16x16x32_bf16(hh[rt], UhH, ahh[rt], 0, 0, 0);
            ahh[rt] = __builtin_amdgcn_mfma_f32_16x16x32_bf16(hl[rt], UhH, ahh[rt], 0, 0, 0);
            ahh[rt] = __builtin_amdgcn_mfma_f32_16x16x32_bf16(hh[rt], UhL, ahh[rt], 0, 0, 0);
        }
    }
#undef WB

    __syncthreads();   // all reads of hbh/hbl done before in-place writes

    const int c = w * 16 + m16;
    const float bz  = bias[c] + bias[384 + c];
    const float br  = bias[128 + c] + bias[512 + c];
    const float bxh = bias[256 + c];
    const float brh = bias[640 + c];

#pragma unroll
    for (int rt = 0; rt < 4; rt++) {
#pragma unroll
        for (int reg = 0; reg < 4; reg++) {
            const int row = e0 + rt * 16 + quad * 4 + reg;
            if (row < E_NUM) {
                const float z  = 1.f / (1.f + expf(-(az[rt][reg] + bz)));
                const float r  = 1.f / (1.f + expf(-(ar[rt][reg] + br)));
                const float hc = tanhf(ahx[rt][reg] + bxh + r * (ahh[rt][reg] + brh));
                const size_t g = (size_t)row * DIM + c;
                const float hp = bf2f(hbh[g]) + bf2f(hbl[g]);
                const float hn = z * hp + (1.f - z) * hc;
                const ushort_t hi = f2bf(hn);
                hbh[g] = hi;
                hbl[g] = f2bf(hn - bf2f(hi));
            }
        }
    }
}

// ===========================================================================
// Graph pooling + readout
// ===========================================================================
__global__ __launch_bounds__(256)
void pool_kernel(const ushort_t* __restrict__ hbh, const ushort_t* __restrict__ hbl,
                 const int* __restrict__ gid, float* __restrict__ pooled)
{
    const int idx = blockIdx.x * 256 + threadIdx.x;
    const int e = idx >> 7;
    const int n = idx & 127;
    const float hv = bf2f(hbh[idx]) + bf2f(hbl[idx]);
    atomicAdd(pooled + (size_t)gid[e] * DIM + n, hv);
}

__global__ __launch_bounds__(256)
void readout_kernel(const float* __restrict__ pooled,
                    const float* __restrict__ W1, const float* __restrict__ b1,
                    const float* __restrict__ W2, const float* __restrict__ b2,
                    const float* __restrict__ W3, const float* __restrict__ b3,
                    float* __restrict__ out)
{
    __shared__ float sp[DIM];
    __shared__ float s1[R_UNITS];
    __shared__ float s2[R_UNITS];
    const int g = blockIdx.x, tid = threadIdx.x;

    if (tid < DIM) sp[tid] = pooled[(size_t)g * DIM + tid];
    __syncthreads();

    float acc = b1[tid];
    for (int k = 0; k < DIM; k++) acc += sp[k] * W1[(size_t)k * R_UNITS + tid];
    s1[tid] = selu_f(acc);
    __syncthreads();

    acc = b2[tid];
    for (int k = 0; k < R_UNITS; k++) acc += s1[k] * W2[(size_t)k * R_UNITS + tid];
    s2[tid] = selu_f(acc) * W3[tid];
    __syncthreads();

    for (int s = 128; s > 0; s >>= 1) {
        if (tid < s) s2[tid] += s2[tid + s];
        __syncthreads();
    }
    if (tid == 0) out[g] = s2[0] + b3[0];
}

// ===========================================================================
extern "C" void kernel_launch(void* const* d_in, const int* in_sizes, int n_in,
                              void* d_out, int out_size, void* d_ws, size_t ws_size,
                              hipStream_t stream)
{
    const float* link_state = (const float*)d_in[0];
    const int*   gids       = (const int*)d_in[1];
    const int*   first      = (const int*)d_in[2];
    const int*   second     = (const int*)d_in[3];
    const float* Wmsg       = (const float*)d_in[5];
    const float* bmsg       = (const float*)d_in[6];
    const float* gK         = (const float*)d_in[7];
    const float* gU         = (const float*)d_in[8];
    const float* gbias      = (const float*)d_in[9];
    const float* W1         = (const float*)d_in[10];
    const float* b1         = (const float*)d_in[11];
    const float* W2         = (const float*)d_in[12];
    const float* b2         = (const float*)d_in[13];
    const float* W3         = (const float*)d_in[14];
    const float* b3         = (const float*)d_in[15];
    float* out = (float*)d_out;

    // ws layout (16B-aligned segments), ~154 MiB total:
    //   offsets[100004] counts[1e5] cursor[1e5] bsum[128] sfirst[P] ssecond[P]
    //   wt[32768 us] wy[32768 us] wb[196608 us]
    //   hb_hi[E*128 us] hb_lo[E*128 us] agg[E*128 f32] Y2[E*128 f32]
    int* offsets = (int*)d_ws;
    int* counts  = offsets + 100004;
    int* cursor  = counts + E_NUM;
    int* bsum    = cursor + E_NUM;
    int* sfirst  = bsum + 128;
    int* ssecond = sfirst + P_NUM;
    ushort_t* wt    = (ushort_t*)(ssecond + P_NUM);
    ushort_t* wy    = wt + 32768;
    ushort_t* wb    = wy + 32768;
    ushort_t* hb_hi = wb + 196608;
    ushort_t* hb_lo = hb_hi + (size_t)E_NUM * DIM;
    float*    agg   = (float*)(hb_lo + (size_t)E_NUM * DIM);
    float*    Y2    = agg + (size_t)E_NUM * DIM;

    const size_t agg_bytes = (size_t)E_NUM * DIM * sizeof(float);

    // ---- one-time prep ----
    hipMemsetAsync(counts, 0, E_NUM * sizeof(int), stream);
    hipMemsetAsync(cursor, 0, E_NUM * sizeof(int), stream);
    hist_kernel<<<P_NUM / 256, 256, 0, stream>>>(second, counts);
    scanA_kernel<<<98, 1024, 0, stream>>>(counts, offsets, bsum);
    scanB_kernel<<<1, 1, 0, stream>>>(bsum, offsets);
    scanC_kernel<<<98, 1024, 0, stream>>>(offsets, bsum);
    fill_kernel<<<P_NUM / 256, 256, 0, stream>>>(first, second, offsets, cursor,
                                                 sfirst, ssecond);
    wsplit_build_kernel<<<32, 256, 0, stream>>>(Wmsg, wt, wy);
    wb_build_kernel<<<96, 256, 0, stream>>>(gK, gU, wb);
    cast_h_kernel<<<(E_NUM * DIM) / 256, 256, 0, stream>>>(link_state, hb_hi, hb_lo);

    // ---- message-passing steps ----
    for (int t = 0; t < T_STEPS; t++) {
        y2_kernel<<<E_NUM / 32, 256, 0, stream>>>(hb_hi, hb_lo, wy, Y2);
        hipMemsetAsync(agg, 0, agg_bytes, stream);
        msg_kernel<<<P_NUM / 128, 256, 0, stream>>>(hb_hi, hb_lo, sfirst, ssecond,
                                                    wt, Y2, bmsg, agg);
        gru_kernel<<<(E_NUM + 63) / 64, 512, 0, stream>>>(agg, hb_hi, hb_lo,
                                                          wb, gbias);
    }

    // ---- pool + readout ----
    float* pooled = agg;  // reuse
    hipMemsetAsync(pooled, 0, (size_t)G_NUM * DIM * sizeof(float), stream);
    pool_kernel<<<(E_NUM * DIM) / 256, 256, 0, stream>>>(hb_hi, hb_lo, gids, pooled);
    readout_kernel<<<G_NUM, 256, 0, stream>>>(pooled, W1, b1, W2, b2, W3, b3, out);
}

// Round 11
// 4499.719 us; speedup vs baseline: 1.1103x; 1.1103x over previous
//
#include <hip/hip_runtime.h>
#include <math.h>

#define DIM 128
#define E_NUM 100000
#define P_NUM 800000
#define G_NUM 1000
#define T_STEPS 8
#define R_UNITS 256

typedef __attribute__((ext_vector_type(8))) short bf16x8;   // 8 bf16 = 4 VGPRs
typedef __attribute__((ext_vector_type(4))) float f32x4;    // 16x16 MFMA acc

typedef unsigned short ushort_t;
typedef unsigned int   uint_t;

__device__ __forceinline__ float selu_f(float x) {
    const float alpha = 1.6732632423543772f;
    const float scale = 1.0507009873554805f;
    return x > 0.f ? scale * x : scale * alpha * expm1f(x);
}

__device__ __forceinline__ ushort_t f2bf(float x) {
    uint_t u = __float_as_uint(x);
    uint_t r = (u + 0x7fffu + ((u >> 16) & 1u)) >> 16;
    return (ushort_t)r;
}
__device__ __forceinline__ float bf2f(ushort_t h) {
    return __uint_as_float(((uint_t)h) << 16);
}

// ===========================================================================
// CSR build (once per launch). Multi-block scan.
// ===========================================================================
__global__ __launch_bounds__(256)
void hist_kernel(const int* __restrict__ second, int* __restrict__ counts)
{
    const int p = blockIdx.x * 256 + threadIdx.x;
    atomicAdd(&counts[second[p]], 1);
}

__global__ __launch_bounds__(1024)
void scanA_kernel(const int* __restrict__ counts, int* __restrict__ offsets,
                  int* __restrict__ bsum)
{
    __shared__ int buf[1024];
    const int i = blockIdx.x * 1024 + threadIdx.x;
    const int v = (i < E_NUM) ? counts[i] : 0;
    buf[threadIdx.x] = v;
    __syncthreads();
    for (int off = 1; off < 1024; off <<= 1) {
        const int t = (threadIdx.x >= off) ? buf[threadIdx.x - off] : 0;
        __syncthreads();
        buf[threadIdx.x] += t;
        __syncthreads();
    }
    if (i < E_NUM) offsets[i] = buf[threadIdx.x] - v;   // block-local exclusive
    if (threadIdx.x == 1023) bsum[blockIdx.x] = buf[1023];
}

__global__ void scanB_kernel(int* __restrict__ bsum, int* __restrict__ offsets)
{
    int acc = 0;
    for (int b = 0; b < 98; b++) { const int t = bsum[b]; bsum[b] = acc; acc += t; }
    offsets[E_NUM] = P_NUM;
}

__global__ __launch_bounds__(1024)
void scanC_kernel(int* __restrict__ offsets, const int* __restrict__ bsum)
{
    const int i = blockIdx.x * 1024 + threadIdx.x;
    if (i < E_NUM) offsets[i] += bsum[blockIdx.x];
}

__global__ __launch_bounds__(256)
void fill_kernel(const int* __restrict__ first, const int* __restrict__ second,
                 const int* __restrict__ offsets, int* __restrict__ cursor,
                 int* __restrict__ sfirst, int* __restrict__ ssecond)
{
    const int p = blockIdx.x * 256 + threadIdx.x;
    const int d = second[p];
    const int pos = atomicAdd(&cursor[d], 1);
    const int idx = offsets[d] + pos;
    sfirst[idx] = first[p];
    ssecond[idx] = d;
}

// ===========================================================================
// One-time prep (unchanged).
// ===========================================================================
__global__ __launch_bounds__(256)
void cast_h_kernel(const float* __restrict__ src,
                   ushort_t* __restrict__ dhi, ushort_t* __restrict__ dlo)
{
    const int idx = blockIdx.x * 256 + threadIdx.x;
    const float x = src[idx];
    const ushort_t hi = f2bf(x);
    dhi[idx] = hi;
    dlo[idx] = f2bf(x - bf2f(hi));
}

__global__ __launch_bounds__(256)
void wsplit_build_kernel(const float* __restrict__ Wmsg,
                         ushort_t* __restrict__ wt, ushort_t* __restrict__ wy)
{
    const int idx  = blockIdx.x * 256 + threadIdx.x;   // 8192 slots (2 halves)
    const int lane = idx & 63;
    const int nt   = (idx >> 6) & 7;
    const int comp = (idx >> 9) & 1;
    const int ks   = (idx >> 10) & 3;
    const int half = idx >> 12;
    const int n    = nt * 16 + (lane & 15);
    const int kb   = ks * 32 + (lane >> 4) * 8 + half * 128;
    ushort_t* dst  = half ? wy : wt;
    const int slot = idx & 4095;
#pragma unroll
    for (int j = 0; j < 8; j++) {
        const float w = Wmsg[(size_t)(kb + j) * DIM + n];
        const ushort_t hi = f2bf(w);
        dst[(size_t)slot * 8 + j] = comp ? f2bf(w - bf2f(hi)) : hi;
    }
}

__global__ __launch_bounds__(256)
void wb_build_kernel(const float* __restrict__ K, const float* __restrict__ U,
                     ushort_t* __restrict__ wb)
{
    const int idx  = blockIdx.x * 256 + threadIdx.x;   // 24576 slots
    const int lane = idx & 63;
    int t = idx >> 6;
    const int nt   = t % 24;  t /= 24;
    const int comp = t & 1;   t >>= 1;
    const int gemm = t & 1;
    const int ks   = t >> 1;
    const float* src = gemm ? U : K;
    const int n  = nt * 16 + (lane & 15);
    const int kb = ks * 32 + (lane >> 4) * 8;
#pragma unroll
    for (int j = 0; j < 8; j++) {
        const float w = src[(size_t)(kb + j) * 384 + n];
        const ushort_t hi = f2bf(w);
        wb[(size_t)idx * 8 + j] = comp ? f2bf(w - bf2f(hi)) : hi;
    }
}

// ===========================================================================
// GY kernel: per step, compute BOTH per-edge GEMMs in one pass:
//   G[e]   = h[e] @ W_top            (f32, no bias)
//   Y2b[e] = h[e] @ W_bot + bmsg     (f32, bias folded)
// Block 256 thr (4 waves), M=32 edges (3125 blocks), N=256 (wave w owns
// n-tiles w*4..w*4+3 of the combined output). bf16x3.
// ===========================================================================
__global__ __launch_bounds__(256, 4)
void gy_kernel(const ushort_t* __restrict__ hbh, const ushort_t* __restrict__ hbl,
               const ushort_t* __restrict__ wt, const ushort_t* __restrict__ wy,
               const float* __restrict__ bmsg,
               float* __restrict__ G, float* __restrict__ Y2b)
{
    const int tid  = threadIdx.x;
    const int lane = tid & 63;
    const int w    = tid >> 6;
    const int e0   = blockIdx.x * 32;
    const int m16  = lane & 15;
    const int quad = lane >> 4;

    f32x4 acc[2][4] = {};
#pragma unroll
    for (int ks = 0; ks < 4; ks++) {
        const int koff = ks * 32 + quad * 8;
        bf16x8 ah[2], al[2];
#pragma unroll
        for (int rt = 0; rt < 2; rt++) {
            const size_t row = (size_t)(e0 + rt * 16 + m16);
            ah[rt] = *(const bf16x8*)(hbh + row * DIM + koff);
            al[rt] = *(const bf16x8*)(hbl + row * DIM + koff);
        }
#pragma unroll
        for (int ntl = 0; ntl < 4; ntl++) {
            const int ntg = w * 4 + ntl;                    // 0..15
            const ushort_t* wsel = (ntg < 8) ? wt : wy;
            const int nt = ntg & 7;
            const bf16x8 bh = *(const bf16x8*)(wsel + (size_t)(((ks * 2 + 0) * 8 + nt) * 64 + lane) * 8);
            const bf16x8 bl = *(const bf16x8*)(wsel + (size_t)(((ks * 2 + 1) * 8 + nt) * 64 + lane) * 8);
#pragma unroll
            for (int rt = 0; rt < 2; rt++) {
                acc[rt][ntl] = __builtin_amdgcn_mfma_f32_16x16x32_bf16(ah[rt], bh, acc[rt][ntl], 0, 0, 0);
                acc[rt][ntl] = __builtin_amdgcn_mfma_f32_16x16x32_bf16(al[rt], bh, acc[rt][ntl], 0, 0, 0);
                acc[rt][ntl] = __builtin_amdgcn_mfma_f32_16x16x32_bf16(ah[rt], bl, acc[rt][ntl], 0, 0, 0);
            }
        }
    }
    // C layout: col = lane&15, row = quad*4 + reg
#pragma unroll
    for (int ntl = 0; ntl < 4; ntl++) {
        const int ntg = w * 4 + ntl;
        const int c   = (ntg & 7) * 16 + m16;               // 0..127 within half
        const bool isG = (ntg < 8);
        const float bb = isG ? 0.f : bmsg[c];
        float* dst = isG ? G : Y2b;
#pragma unroll
        for (int rt = 0; rt < 2; rt++) {
#pragma unroll
            for (int reg = 0; reg < 4; reg++) {
                const size_t row = (size_t)(e0 + rt * 16 + quad * 4 + reg);
                dst[row * DIM + c] = acc[rt][ntl][reg] + bb;
            }
        }
    }
}

// ===========================================================================
// msg_lite: agg[d] = sum_{p: second[p]=d} selu(G[first_p] + Y2b[d])
// NO MFMA — pure streaming. Block 256 thr, 64 pairs (12500 blocks).
// Phase 1: thread (s=tid>>2, cg=tid&3) loads 8 float4 of G[f_s] + 8 float4
//   of Y2b[d] (L1-hot, runs share d), selu, writes to LDS Ms.
// Phase 2: R4-proven leader segmented reduction by destination: plain
//   float4 stores for interior runs, atomicAdd only at block boundaries.
// 16 independent loads/thread -> deep vmcnt pipeline, no MFMA serialization.
// ===========================================================================
#define MT 64
#define MS_STRIDE 132

__global__ __launch_bounds__(256)
void msg_lite_kernel(const float* __restrict__ G, const float* __restrict__ Y2b,
                     const int* __restrict__ sfirst, const int* __restrict__ ssecond,
                     float* __restrict__ agg)
{
    __shared__ float Ms[MT * MS_STRIDE];          // 33792 B
    __shared__ int f_s[MT], s_sh[MT];
    __shared__ int prevdst, nextdst;

    const int tid = threadIdx.x;
    const int p0  = blockIdx.x * MT;

    if (tid < MT) {
        f_s[tid]  = sfirst[p0 + tid];
        s_sh[tid] = ssecond[p0 + tid];
    }
    if (tid == 64) prevdst = (p0 == 0) ? -1 : ssecond[p0 - 1];
    if (tid == 65) nextdst = (p0 + MT >= P_NUM) ? -1 : ssecond[p0 + MT];
    __syncthreads();

    // ---- phase 1: gather + selu -> LDS ----
    {
        const int s  = tid >> 2;         // pair slot
        const int cg = tid & 3;          // col group of 32
        const float* gp = G   + (size_t)f_s[s]  * DIM + cg * 32;
        const float* yp = Y2b + (size_t)s_sh[s] * DIM + cg * 32;
        float4 gv[8], yv[8];
#pragma unroll
        for (int i = 0; i < 8; i++) gv[i] = ((const float4*)gp)[i];
#pragma unroll
        for (int i = 0; i < 8; i++) yv[i] = ((const float4*)yp)[i];
        float* mrow = Ms + s * MS_STRIDE + cg * 32;
#pragma unroll
        for (int i = 0; i < 8; i++) {
            float4 o;
            o.x = selu_f(gv[i].x + yv[i].x);
            o.y = selu_f(gv[i].y + yv[i].y);
            o.z = selu_f(gv[i].z + yv[i].z);
            o.w = selu_f(gv[i].w + yv[i].w);
            *(float4*)(mrow + i * 4) = o;
        }
    }
    __syncthreads();

    // ---- phase 2: segmented reduction by destination ----
    const int r  = tid & 63;
    const int cg = tid >> 6;
    const int d  = s_sh[r];
    const bool leader = (r == 0) || (d != s_sh[r - 1]);
    if (leader) {
        int end = r + 1;
        while (end < MT && s_sh[end] == d) end++;
        const bool needs_atomic = (r == 0 && d == prevdst) ||
                                  (end == MT && d == nextdst);
        float sacc[32];
#pragma unroll
        for (int c = 0; c < 32; c++) sacc[c] = 0.f;
        for (int rr = r; rr < end; rr++) {
            const float* mrow = Ms + rr * MS_STRIDE + cg * 32;
#pragma unroll
            for (int c = 0; c < 32; c++) sacc[c] += mrow[c];
        }
        float* dst = agg + (size_t)d * DIM + cg * 32;
        if (needs_atomic) {
#pragma unroll
            for (int c = 0; c < 32; c++) atomicAdd(dst + c, sacc[c]);
        } else {
#pragma unroll
            for (int c4 = 0; c4 < 8; c4++) {
                float4 v = make_float4(sacc[c4 * 4], sacc[c4 * 4 + 1],
                                       sacc[c4 * 4 + 2], sacc[c4 * 4 + 3]);
                *(float4*)(dst + c4 * 4) = v;
            }
        }
    }
}

// ===========================================================================
// GRU kernel, register-gates (R9 version — fence reverted).
// ===========================================================================
__global__ __launch_bounds__(512, 3)
void gru_kernel(const float* __restrict__ agg,
                ushort_t* __restrict__ hbh, ushort_t* __restrict__ hbl,
                const ushort_t* __restrict__ wb, const float* __restrict__ bias)
{
    const int tid  = threadIdx.x;
    const int lane = tid & 63;
    const int w    = tid >> 6;          // 0..7
    const int e0   = blockIdx.x * 64;
    const int m16  = lane & 15;
    const int quad = lane >> 4;

    f32x4 az[4] = {}, ar[4] = {}, ahx[4] = {}, ahh[4] = {};

#define WB(ks_, gm_, cp_, nt_) \
    (*(const bf16x8*)(wb + ((size_t)(((ks_) * 96) + (gm_) * 48 + (cp_) * 24 + (nt_)) * 64 + lane) * 8))

#pragma unroll
    for (int ks = 0; ks < 4; ks++) {
        const int koff = ks * 32 + quad * 8;
        const bf16x8 KzH = WB(ks, 0, 0, w),      KzL = WB(ks, 0, 1, w);
        const bf16x8 UzH = WB(ks, 1, 0, w),      UzL = WB(ks, 1, 1, w);
        const bf16x8 KrH = WB(ks, 0, 0, w + 8),  KrL = WB(ks, 0, 1, w + 8);
        const bf16x8 UrH = WB(ks, 1, 0, w + 8),  UrL = WB(ks, 1, 1, w + 8);
        const bf16x8 KhH = WB(ks, 0, 0, w + 16), KhL = WB(ks, 0, 1, w + 16);
        const bf16x8 UhH = WB(ks, 1, 0, w + 16), UhL = WB(ks, 1, 1, w + 16);
#pragma unroll
        for (int rt = 0; rt < 4; rt++) {
            int row = e0 + rt * 16 + m16;
            if (row >= E_NUM) row = E_NUM - 1;
            const float* xp = agg + (size_t)row * DIM + koff;
            const float4 v0 = *(const float4*)xp;
            const float4 v1 = *(const float4*)(xp + 4);
            const float xv[8] = {v0.x, v0.y, v0.z, v0.w, v1.x, v1.y, v1.z, v1.w};
            bf16x8 xh, xl;
#pragma unroll
            for (int j = 0; j < 8; j++) {
                const ushort_t hi = f2bf(xv[j]);
                xh[j] = (short)hi;
                xl[j] = (short)f2bf(xv[j] - bf2f(hi));
            }
            const bf16x8 hh = *(const bf16x8*)(hbh + (size_t)row * DIM + koff);
            const bf16x8 hl = *(const bf16x8*)(hbl + (size_t)row * DIM + koff);

            az[rt] = __builtin_amdgcn_mfma_f32_16x16x32_bf16(xh, KzH, az[rt], 0, 0, 0);
            az[rt] = __builtin_amdgcn_mfma_f32_16x16x32_bf16(xl, KzH, az[rt], 0, 0, 0);
            az[rt] = __builtin_amdgcn_mfma_f32_16x16x32_bf16(xh, KzL, az[rt], 0, 0, 0);
            az[rt] = __builtin_amdgcn_mfma_f32_16x16x32_bf16(hh, UzH, az[rt], 0, 0, 0);
            az[rt] = __builtin_amdgcn_mfma_f32_16x16x32_bf16(hl, UzH, az[rt], 0, 0, 0);
            az[rt] = __builtin_amdgcn_mfma_f32_16x16x32_bf16(hh, UzL, az[rt], 0, 0, 0);

            ar[rt] = __builtin_amdgcn_mfma_f32_16x16x32_bf16(xh, KrH, ar[rt], 0, 0, 0);
            ar[rt] = __builtin_amdgcn_mfma_f32_16x16x32_bf16(xl, KrH, ar[rt], 0, 0, 0);
            ar[rt] = __builtin_amdgcn_mfma_f32_16x16x32_bf16(xh, KrL, ar[rt], 0, 0, 0);
            ar[rt] = __builtin_amdgcn_mfma_f32_16x16x32_bf16(hh, UrH, ar[rt], 0, 0, 0);
            ar[rt] = __builtin_amdgcn_mfma_f32_16x16x32_bf16(hl, UrH, ar[rt], 0, 0, 0);
            ar[rt] = __builtin_amdgcn_mfma_f32_16x16x32_bf16(hh, UrL, ar[rt], 0, 0, 0);

            ahx[rt] = __builtin_amdgcn_mfma_f32_16x16x32_bf16(xh, KhH, ahx[rt], 0, 0, 0);
            ahx[rt] = __builtin_amdgcn_mfma_f32_16x16x32_bf16(xl, KhH, ahx[rt], 0, 0, 0);
            ahx[rt] = __builtin_amdgcn_mfma_f32_16x16x32_bf16(xh, KhL, ahx[rt], 0, 0, 0);
            ahh[rt] = __builtin_amdgcn_mfma_f32_16x16x32_bf16(hh, UhH, ahh[rt], 0, 0, 0);
            ahh[rt] = __builtin_amdgcn_mfma_f32_16x16x32_bf16(hl, UhH, ahh[rt], 0, 0, 0);
            ahh[rt] = __builtin_amdgcn_mfma_f32_16x16x32_bf16(hh, UhL, ahh[rt], 0, 0, 0);
        }
    }
#undef WB

    __syncthreads();   // all reads of hbh/hbl done before in-place writes

    const int c = w * 16 + m16;
    const float bz  = bias[c] + bias[384 + c];
    const float br  = bias[128 + c] + bias[512 + c];
    const float bxh = bias[256 + c];
    const float brh = bias[640 + c];

#pragma unroll
    for (int rt = 0; rt < 4; rt++) {
#pragma unroll
        for (int reg = 0; reg < 4; reg++) {
            const int row = e0 + rt * 16 + quad * 4 + reg;
            if (row < E_NUM) {
                const float z  = 1.f / (1.f + expf(-(az[rt][reg] + bz)));
                const float r  = 1.f / (1.f + expf(-(ar[rt][reg] + br)));
                const float hc = tanhf(ahx[rt][reg] + bxh + r * (ahh[rt][reg] + brh));
                const size_t g = (size_t)row * DIM + c;
                const float hp = bf2f(hbh[g]) + bf2f(hbl[g]);
                const float hn = z * hp + (1.f - z) * hc;
                const ushort_t hi = f2bf(hn);
                hbh[g] = hi;
                hbl[g] = f2bf(hn - bf2f(hi));
            }
        }
    }
}

// ===========================================================================
// Graph pooling + readout
// ===========================================================================
__global__ __launch_bounds__(256)
void pool_kernel(const ushort_t* __restrict__ hbh, const ushort_t* __restrict__ hbl,
                 const int* __restrict__ gid, float* __restrict__ pooled)
{
    const int idx = blockIdx.x * 256 + threadIdx.x;
    const int e = idx >> 7;
    const int n = idx & 127;
    const float hv = bf2f(hbh[idx]) + bf2f(hbl[idx]);
    atomicAdd(pooled + (size_t)gid[e] * DIM + n, hv);
}

__global__ __launch_bounds__(256)
void readout_kernel(const float* __restrict__ pooled,
                    const float* __restrict__ W1, const float* __restrict__ b1,
                    const float* __restrict__ W2, const float* __restrict__ b2,
                    const float* __restrict__ W3, const float* __restrict__ b3,
                    float* __restrict__ out)
{
    __shared__ float sp[DIM];
    __shared__ float s1[R_UNITS];
    __shared__ float s2[R_UNITS];
    const int g = blockIdx.x, tid = threadIdx.x;

    if (tid < DIM) sp[tid] = pooled[(size_t)g * DIM + tid];
    __syncthreads();

    float acc = b1[tid];
    for (int k = 0; k < DIM; k++) acc += sp[k] * W1[(size_t)k * R_UNITS + tid];
    s1[tid] = selu_f(acc);
    __syncthreads();

    acc = b2[tid];
    for (int k = 0; k < R_UNITS; k++) acc += s1[k] * W2[(size_t)k * R_UNITS + tid];
    s2[tid] = selu_f(acc) * W3[tid];
    __syncthreads();

    for (int s = 128; s > 0; s >>= 1) {
        if (tid < s) s2[tid] += s2[tid + s];
        __syncthreads();
    }
    if (tid == 0) out[g] = s2[0] + b3[0];
}

// ===========================================================================
extern "C" void kernel_launch(void* const* d_in, const int* in_sizes, int n_in,
                              void* d_out, int out_size, void* d_ws, size_t ws_size,
                              hipStream_t stream)
{
    const float* link_state = (const float*)d_in[0];
    const int*   gids       = (const int*)d_in[1];
    const int*   first      = (const int*)d_in[2];
    const int*   second     = (const int*)d_in[3];
    const float* Wmsg       = (const float*)d_in[5];
    const float* bmsg       = (const float*)d_in[6];
    const float* gK         = (const float*)d_in[7];
    const float* gU         = (const float*)d_in[8];
    const float* gbias      = (const float*)d_in[9];
    const float* W1         = (const float*)d_in[10];
    const float* b1         = (const float*)d_in[11];
    const float* W2         = (const float*)d_in[12];
    const float* b2         = (const float*)d_in[13];
    const float* W3         = (const float*)d_in[14];
    const float* b3         = (const float*)d_in[15];
    float* out = (float*)d_out;

    // ws layout (16B-aligned segments), ~205 MiB total:
    //   offsets[100004] counts[1e5] cursor[1e5] bsum[128] sfirst[P] ssecond[P]
    //   wt[32768 us] wy[32768 us] wb[196608 us]
    //   hb_hi[E*128 us] hb_lo[E*128 us] agg[E*128 f32] G[E*128 f32] Y2b[E*128 f32]
    int* offsets = (int*)d_ws;
    int* counts  = offsets + 100004;
    int* cursor  = counts + E_NUM;
    int* bsum    = cursor + E_NUM;
    int* sfirst  = bsum + 128;
    int* ssecond = sfirst + P_NUM;
    ushort_t* wt    = (ushort_t*)(ssecond + P_NUM);
    ushort_t* wy    = wt + 32768;
    ushort_t* wb    = wy + 32768;
    ushort_t* hb_hi = wb + 196608;
    ushort_t* hb_lo = hb_hi + (size_t)E_NUM * DIM;
    float*    agg   = (float*)(hb_lo + (size_t)E_NUM * DIM);
    float*    G     = agg + (size_t)E_NUM * DIM;
    float*    Y2b   = G   + (size_t)E_NUM * DIM;

    const size_t agg_bytes = (size_t)E_NUM * DIM * sizeof(float);

    // ---- one-time prep ----
    hipMemsetAsync(counts, 0, E_NUM * sizeof(int), stream);
    hipMemsetAsync(cursor, 0, E_NUM * sizeof(int), stream);
    hist_kernel<<<P_NUM / 256, 256, 0, stream>>>(second, counts);
    scanA_kernel<<<98, 1024, 0, stream>>>(counts, offsets, bsum);
    scanB_kernel<<<1, 1, 0, stream>>>(bsum, offsets);
    scanC_kernel<<<98, 1024, 0, stream>>>(offsets, bsum);
    fill_kernel<<<P_NUM / 256, 256, 0, stream>>>(first, second, offsets, cursor,
                                                 sfirst, ssecond);
    wsplit_build_kernel<<<32, 256, 0, stream>>>(Wmsg, wt, wy);
    wb_build_kernel<<<96, 256, 0, stream>>>(gK, gU, wb);
    cast_h_kernel<<<(E_NUM * DIM) / 256, 256, 0, stream>>>(link_state, hb_hi, hb_lo);

    // ---- message-passing steps ----
    for (int t = 0; t < T_STEPS; t++) {
        gy_kernel<<<E_NUM / 32, 256, 0, stream>>>(hb_hi, hb_lo, wt, wy, bmsg,
                                                  G, Y2b);
        hipMemsetAsync(agg, 0, agg_bytes, stream);
        msg_lite_kernel<<<P_NUM / MT, 256, 0, stream>>>(G, Y2b, sfirst, ssecond,
                                                        agg);
        gru_kernel<<<(E_NUM + 63) / 64, 512, 0, stream>>>(agg, hb_hi, hb_lo,
                                                          wb, gbias);
    }

    // ---- pool + readout ----
    float* pooled = agg;  // reuse
    hipMemsetAsync(pooled, 0, (size_t)G_NUM * DIM * sizeof(float), stream);
    pool_kernel<<<(E_NUM * DIM) / 256, 256, 0, stream>>>(hb_hi, hb_lo, gids, pooled);
    readout_kernel<<<G_NUM, 256, 0, stream>>>(pooled, W1, b1, W2, b2, W3, b3, out);
}

// Round 12
// 3013.584 us; speedup vs baseline: 1.6579x; 1.4931x over previous
//
#include <hip/hip_runtime.h>
#include <math.h>

#define DIM 128
#define E_NUM 100000
#define P_NUM 800000
#define G_NUM 1000
#define T_STEPS 8
#define R_UNITS 256

typedef __attribute__((ext_vector_type(8))) short bf16x8;   // 8 bf16 = 4 VGPRs
typedef __attribute__((ext_vector_type(4))) float f32x4;    // 16x16 MFMA acc

typedef unsigned short ushort_t;
typedef unsigned int   uint_t;

__device__ __forceinline__ float selu_f(float x) {
    const float alpha = 1.6732632423543772f;
    const float scale = 1.0507009873554805f;
    return x > 0.f ? scale * x : scale * alpha * expm1f(x);
}

__device__ __forceinline__ ushort_t f2bf(float x) {
    uint_t u = __float_as_uint(x);
    uint_t r = (u + 0x7fffu + ((u >> 16) & 1u)) >> 16;
    return (ushort_t)r;
}
__device__ __forceinline__ float bf2f(ushort_t h) {
    return __uint_as_float(((uint_t)h) << 16);
}

// ===========================================================================
// CSR build (once per launch). Multi-block scan.
// ===========================================================================
__global__ __launch_bounds__(256)
void hist_kernel(const int* __restrict__ second, int* __restrict__ counts)
{
    const int p = blockIdx.x * 256 + threadIdx.x;
    atomicAdd(&counts[second[p]], 1);
}

__global__ __launch_bounds__(1024)
void scanA_kernel(const int* __restrict__ counts, int* __restrict__ offsets,
                  int* __restrict__ bsum)
{
    __shared__ int buf[1024];
    const int i = blockIdx.x * 1024 + threadIdx.x;
    const int v = (i < E_NUM) ? counts[i] : 0;
    buf[threadIdx.x] = v;
    __syncthreads();
    for (int off = 1; off < 1024; off <<= 1) {
        const int t = (threadIdx.x >= off) ? buf[threadIdx.x - off] : 0;
        __syncthreads();
        buf[threadIdx.x] += t;
        __syncthreads();
    }
    if (i < E_NUM) offsets[i] = buf[threadIdx.x] - v;   // block-local exclusive
    if (threadIdx.x == 1023) bsum[blockIdx.x] = buf[1023];
}

__global__ void scanB_kernel(int* __restrict__ bsum, int* __restrict__ offsets)
{
    int acc = 0;
    for (int b = 0; b < 98; b++) { const int t = bsum[b]; bsum[b] = acc; acc += t; }
    offsets[E_NUM] = P_NUM;
}

__global__ __launch_bounds__(1024)
void scanC_kernel(int* __restrict__ offsets, const int* __restrict__ bsum)
{
    const int i = blockIdx.x * 1024 + threadIdx.x;
    if (i < E_NUM) offsets[i] += bsum[blockIdx.x];
}

__global__ __launch_bounds__(256)
void fill_kernel(const int* __restrict__ first, const int* __restrict__ second,
                 const int* __restrict__ offsets, int* __restrict__ cursor,
                 int* __restrict__ sfirst, int* __restrict__ ssecond)
{
    const int p = blockIdx.x * 256 + threadIdx.x;
    const int d = second[p];
    const int pos = atomicAdd(&cursor[d], 1);
    const int idx = offsets[d] + pos;
    sfirst[idx] = first[p];
    ssecond[idx] = d;
}

// ===========================================================================
// One-time prep (unchanged).
// ===========================================================================
__global__ __launch_bounds__(256)
void cast_h_kernel(const float* __restrict__ src,
                   ushort_t* __restrict__ dhi, ushort_t* __restrict__ dlo)
{
    const int idx = blockIdx.x * 256 + threadIdx.x;
    const float x = src[idx];
    const ushort_t hi = f2bf(x);
    dhi[idx] = hi;
    dlo[idx] = f2bf(x - bf2f(hi));
}

__global__ __launch_bounds__(256)
void wsplit_build_kernel(const float* __restrict__ Wmsg,
                         ushort_t* __restrict__ wt, ushort_t* __restrict__ wy)
{
    const int idx  = blockIdx.x * 256 + threadIdx.x;   // 8192 slots (2 halves)
    const int lane = idx & 63;
    const int nt   = (idx >> 6) & 7;
    const int comp = (idx >> 9) & 1;
    const int ks   = (idx >> 10) & 3;
    const int half = idx >> 12;
    const int n    = nt * 16 + (lane & 15);
    const int kb   = ks * 32 + (lane >> 4) * 8 + half * 128;
    ushort_t* dst  = half ? wy : wt;
    const int slot = idx & 4095;
#pragma unroll
    for (int j = 0; j < 8; j++) {
        const float w = Wmsg[(size_t)(kb + j) * DIM + n];
        const ushort_t hi = f2bf(w);
        dst[(size_t)slot * 8 + j] = comp ? f2bf(w - bf2f(hi)) : hi;
    }
}

__global__ __launch_bounds__(256)
void wb_build_kernel(const float* __restrict__ K, const float* __restrict__ U,
                     ushort_t* __restrict__ wb)
{
    const int idx  = blockIdx.x * 256 + threadIdx.x;   // 24576 slots
    const int lane = idx & 63;
    int t = idx >> 6;
    const int nt   = t % 24;  t /= 24;
    const int comp = t & 1;   t >>= 1;
    const int gemm = t & 1;
    const int ks   = t >> 1;
    const float* src = gemm ? U : K;
    const int n  = nt * 16 + (lane & 15);
    const int kb = ks * 32 + (lane >> 4) * 8;
#pragma unroll
    for (int j = 0; j < 8; j++) {
        const float w = src[(size_t)(kb + j) * 384 + n];
        const ushort_t hi = f2bf(w);
        wb[(size_t)idx * 8 + j] = comp ? f2bf(w - bf2f(hi)) : hi;
    }
}

// ===========================================================================
// GY kernel: per step, compute BOTH per-edge GEMMs in one pass:
//   G[e]   = h[e] @ W_top            (f32, no bias)
//   Y2b[e] = h[e] @ W_bot + bmsg     (f32, bias folded)
// ===========================================================================
__global__ __launch_bounds__(256, 4)
void gy_kernel(const ushort_t* __restrict__ hbh, const ushort_t* __restrict__ hbl,
               const ushort_t* __restrict__ wt, const ushort_t* __restrict__ wy,
               const float* __restrict__ bmsg,
               float* __restrict__ G, float* __restrict__ Y2b)
{
    const int tid  = threadIdx.x;
    const int lane = tid & 63;
    const int w    = tid >> 6;
    const int e0   = blockIdx.x * 32;
    const int m16  = lane & 15;
    const int quad = lane >> 4;

    f32x4 acc[2][4] = {};
#pragma unroll
    for (int ks = 0; ks < 4; ks++) {
        const int koff = ks * 32 + quad * 8;
        bf16x8 ah[2], al[2];
#pragma unroll
        for (int rt = 0; rt < 2; rt++) {
            const size_t row = (size_t)(e0 + rt * 16 + m16);
            ah[rt] = *(const bf16x8*)(hbh + row * DIM + koff);
            al[rt] = *(const bf16x8*)(hbl + row * DIM + koff);
        }
#pragma unroll
        for (int ntl = 0; ntl < 4; ntl++) {
            const int ntg = w * 4 + ntl;                    // 0..15
            const ushort_t* wsel = (ntg < 8) ? wt : wy;
            const int nt = ntg & 7;
            const bf16x8 bh = *(const bf16x8*)(wsel + (size_t)(((ks * 2 + 0) * 8 + nt) * 64 + lane) * 8);
            const bf16x8 bl = *(const bf16x8*)(wsel + (size_t)(((ks * 2 + 1) * 8 + nt) * 64 + lane) * 8);
#pragma unroll
            for (int rt = 0; rt < 2; rt++) {
                acc[rt][ntl] = __builtin_amdgcn_mfma_f32_16x16x32_bf16(ah[rt], bh, acc[rt][ntl], 0, 0, 0);
                acc[rt][ntl] = __builtin_amdgcn_mfma_f32_16x16x32_bf16(al[rt], bh, acc[rt][ntl], 0, 0, 0);
                acc[rt][ntl] = __builtin_amdgcn_mfma_f32_16x16x32_bf16(ah[rt], bl, acc[rt][ntl], 0, 0, 0);
            }
        }
    }
    // C layout: col = lane&15, row = quad*4 + reg
#pragma unroll
    for (int ntl = 0; ntl < 4; ntl++) {
        const int ntg = w * 4 + ntl;
        const int c   = (ntg & 7) * 16 + m16;               // 0..127 within half
        const bool isG = (ntg < 8);
        const float bb = isG ? 0.f : bmsg[c];
        float* dst = isG ? G : Y2b;
#pragma unroll
        for (int rt = 0; rt < 2; rt++) {
#pragma unroll
            for (int reg = 0; reg < 4; reg++) {
                const size_t row = (size_t)(e0 + rt * 16 + quad * 4 + reg);
                dst[row * DIM + c] = acc[rt][ntl][reg] + bb;
            }
        }
    }
}

// ===========================================================================
// agg_csr kernel: agg[d] = sum_{p in CSR run of d} selu(G[sfirst[p]] + Y2b[d])
// Wave-per-destination-group: each wave owns 8 consecutive destinations.
// Per destination: read Y2b[d] once (float2/lane), stream the run's G rows
// (float2/lane, 4-way unrolled -> 4 independent gathers in flight), selu-
// accumulate in registers, ONE plain float2 store. No LDS, no atomics, no
// memset (every agg[d] is fully written; empty runs store 0).
// 12500 waves = 3125 blocks x 4; tiny VGPR -> ~8 blocks/CU latency tolerance.
// ===========================================================================
__global__ __launch_bounds__(256)
void agg_csr_kernel(const float* __restrict__ G, const float* __restrict__ Y2b,
                    const int* __restrict__ offsets, const int* __restrict__ sfirst,
                    float* __restrict__ agg)
{
    const int tid  = threadIdx.x;
    const int lane = tid & 63;
    const int wv   = blockIdx.x * 4 + (tid >> 6);   // global wave id, 0..12499
    const int c2   = lane * 2;

#pragma unroll 1
    for (int i = 0; i < 8; i++) {
        const int d = wv * 8 + i;                   // exact: 12500*8 = 100000
        const int start = offsets[d];
        const int end   = offsets[d + 1];
        const float2 y = *(const float2*)(Y2b + (size_t)d * DIM + c2);
        float a0 = 0.f, a1 = 0.f;
        int p = start;
        for (; p + 4 <= end; p += 4) {
            const int f0 = sfirst[p];
            const int f1 = sfirst[p + 1];
            const int f2 = sfirst[p + 2];
            const int f3 = sfirst[p + 3];
            const float2 g0 = *(const float2*)(G + (size_t)f0 * DIM + c2);
            const float2 g1 = *(const float2*)(G + (size_t)f1 * DIM + c2);
            const float2 g2 = *(const float2*)(G + (size_t)f2 * DIM + c2);
            const float2 g3 = *(const float2*)(G + (size_t)f3 * DIM + c2);
            a0 += selu_f(g0.x + y.x);  a1 += selu_f(g0.y + y.y);
            a0 += selu_f(g1.x + y.x);  a1 += selu_f(g1.y + y.y);
            a0 += selu_f(g2.x + y.x);  a1 += selu_f(g2.y + y.y);
            a0 += selu_f(g3.x + y.x);  a1 += selu_f(g3.y + y.y);
        }
        for (; p < end; p++) {
            const int f = sfirst[p];
            const float2 g = *(const float2*)(G + (size_t)f * DIM + c2);
            a0 += selu_f(g.x + y.x);
            a1 += selu_f(g.y + y.y);
        }
        *(float2*)(agg + (size_t)d * DIM + c2) = make_float2(a0, a1);
    }
}

// ===========================================================================
// GRU kernel, register-gates (unchanged from R11).
// ===========================================================================
__global__ __launch_bounds__(512, 3)
void gru_kernel(const float* __restrict__ agg,
                ushort_t* __restrict__ hbh, ushort_t* __restrict__ hbl,
                const ushort_t* __restrict__ wb, const float* __restrict__ bias)
{
    const int tid  = threadIdx.x;
    const int lane = tid & 63;
    const int w    = tid >> 6;          // 0..7
    const int e0   = blockIdx.x * 64;
    const int m16  = lane & 15;
    const int quad = lane >> 4;

    f32x4 az[4] = {}, ar[4] = {}, ahx[4] = {}, ahh[4] = {};

#define WB(ks_, gm_, cp_, nt_) \
    (*(const bf16x8*)(wb + ((size_t)(((ks_) * 96) + (gm_) * 48 + (cp_) * 24 + (nt_)) * 64 + lane) * 8))

#pragma unroll
    for (int ks = 0; ks < 4; ks++) {
        const int koff = ks * 32 + quad * 8;
        const bf16x8 KzH = WB(ks, 0, 0, w),      KzL = WB(ks, 0, 1, w);
        const bf16x8 UzH = WB(ks, 1, 0, w),      UzL = WB(ks, 1, 1, w);
        const bf16x8 KrH = WB(ks, 0, 0, w + 8),  KrL = WB(ks, 0, 1, w + 8);
        const bf16x8 UrH = WB(ks, 1, 0, w + 8),  UrL = WB(ks, 1, 1, w + 8);
        const bf16x8 KhH = WB(ks, 0, 0, w + 16), KhL = WB(ks, 0, 1, w + 16);
        const bf16x8 UhH = WB(ks, 1, 0, w + 16), UhL = WB(ks, 1, 1, w + 16);
#pragma unroll
        for (int rt = 0; rt < 4; rt++) {
            int row = e0 + rt * 16 + m16;
            if (row >= E_NUM) row = E_NUM - 1;
            const float* xp = agg + (size_t)row * DIM + koff;
            const float4 v0 = *(const float4*)xp;
            const float4 v1 = *(const float4*)(xp + 4);
            const float xv[8] = {v0.x, v0.y, v0.z, v0.w, v1.x, v1.y, v1.z, v1.w};
            bf16x8 xh, xl;
#pragma unroll
            for (int j = 0; j < 8; j++) {
                const ushort_t hi = f2bf(xv[j]);
                xh[j] = (short)hi;
                xl[j] = (short)f2bf(xv[j] - bf2f(hi));
            }
            const bf16x8 hh = *(const bf16x8*)(hbh + (size_t)row * DIM + koff);
            const bf16x8 hl = *(const bf16x8*)(hbl + (size_t)row * DIM + koff);

            az[rt] = __builtin_amdgcn_mfma_f32_16x16x32_bf16(xh, KzH, az[rt], 0, 0, 0);
            az[rt] = __builtin_amdgcn_mfma_f32_16x16x32_bf16(xl, KzH, az[rt], 0, 0, 0);
            az[rt] = __builtin_amdgcn_mfma_f32_16x16x32_bf16(xh, KzL, az[rt], 0, 0, 0);
            az[rt] = __builtin_amdgcn_mfma_f32_16x16x32_bf16(hh, UzH, az[rt], 0, 0, 0);
            az[rt] = __builtin_amdgcn_mfma_f32_16x16x32_bf16(hl, UzH, az[rt], 0, 0, 0);
            az[rt] = __builtin_amdgcn_mfma_f32_16x16x32_bf16(hh, UzL, az[rt], 0, 0, 0);

            ar[rt] = __builtin_amdgcn_mfma_f32_16x16x32_bf16(xh, KrH, ar[rt], 0, 0, 0);
            ar[rt] = __builtin_amdgcn_mfma_f32_16x16x32_bf16(xl, KrH, ar[rt], 0, 0, 0);
            ar[rt] = __builtin_amdgcn_mfma_f32_16x16x32_bf16(xh, KrL, ar[rt], 0, 0, 0);
            ar[rt] = __builtin_amdgcn_mfma_f32_16x16x32_bf16(hh, UrH, ar[rt], 0, 0, 0);
            ar[rt] = __builtin_amdgcn_mfma_f32_16x16x32_bf16(hl, UrH, ar[rt], 0, 0, 0);
            ar[rt] = __builtin_amdgcn_mfma_f32_16x16x32_bf16(hh, UrL, ar[rt], 0, 0, 0);

            ahx[rt] = __builtin_amdgcn_mfma_f32_16x16x32_bf16(xh, KhH, ahx[rt], 0, 0, 0);
            ahx[rt] = __builtin_amdgcn_mfma_f32_16x16x32_bf16(xl, KhH, ahx[rt], 0, 0, 0);
            ahx[rt] = __builtin_amdgcn_mfma_f32_16x16x32_bf16(xh, KhL, ahx[rt], 0, 0, 0);
            ahh[rt] = __builtin_amdgcn_mfma_f32_16x16x32_bf16(hh, UhH, ahh[rt], 0, 0, 0);
            ahh[rt] = __builtin_amdgcn_mfma_f32_16x16x32_bf16(hl, UhH, ahh[rt], 0, 0, 0);
            ahh[rt] = __builtin_amdgcn_mfma_f32_16x16x32_bf16(hh, UhL, ahh[rt], 0, 0, 0);
        }
    }
#undef WB

    __syncthreads();   // all reads of hbh/hbl done before in-place writes

    const int c = w * 16 + m16;
    const float bz  = bias[c] + bias[384 + c];
    const float br  = bias[128 + c] + bias[512 + c];
    const float bxh = bias[256 + c];
    const float brh = bias[640 + c];

#pragma unroll
    for (int rt = 0; rt < 4; rt++) {
#pragma unroll
        for (int reg = 0; reg < 4; reg++) {
            const int row = e0 + rt * 16 + quad * 4 + reg;
            if (row < E_NUM) {
                const float z  = 1.f / (1.f + expf(-(az[rt][reg] + bz)));
                const float r  = 1.f / (1.f + expf(-(ar[rt][reg] + br)));
                const float hc = tanhf(ahx[rt][reg] + bxh + r * (ahh[rt][reg] + brh));
                const size_t g = (size_t)row * DIM + c;
                const float hp = bf2f(hbh[g]) + bf2f(hbl[g]);
                const float hn = z * hp + (1.f - z) * hc;
                const ushort_t hi = f2bf(hn);
                hbh[g] = hi;
                hbl[g] = f2bf(hn - bf2f(hi));
            }
        }
    }
}

// ===========================================================================
// Graph pooling + readout
// ===========================================================================
__global__ __launch_bounds__(256)
void pool_kernel(const ushort_t* __restrict__ hbh, const ushort_t* __restrict__ hbl,
                 const int* __restrict__ gid, float* __restrict__ pooled)
{
    const int idx = blockIdx.x * 256 + threadIdx.x;
    const int e = idx >> 7;
    const int n = idx & 127;
    const float hv = bf2f(hbh[idx]) + bf2f(hbl[idx]);
    atomicAdd(pooled + (size_t)gid[e] * DIM + n, hv);
}

__global__ __launch_bounds__(256)
void readout_kernel(const float* __restrict__ pooled,
                    const float* __restrict__ W1, const float* __restrict__ b1,
                    const float* __restrict__ W2, const float* __restrict__ b2,
                    const float* __restrict__ W3, const float* __restrict__ b3,
                    float* __restrict__ out)
{
    __shared__ float sp[DIM];
    __shared__ float s1[R_UNITS];
    __shared__ float s2[R_UNITS];
    const int g = blockIdx.x, tid = threadIdx.x;

    if (tid < DIM) sp[tid] = pooled[(size_t)g * DIM + tid];
    __syncthreads();

    float acc = b1[tid];
    for (int k = 0; k < DIM; k++) acc += sp[k] * W1[(size_t)k * R_UNITS + tid];
    s1[tid] = selu_f(acc);
    __syncthreads();

    acc = b2[tid];
    for (int k = 0; k < R_UNITS; k++) acc += s1[k] * W2[(size_t)k * R_UNITS + tid];
    s2[tid] = selu_f(acc) * W3[tid];
    __syncthreads();

    for (int s = 128; s > 0; s >>= 1) {
        if (tid < s) s2[tid] += s2[tid + s];
        __syncthreads();
    }
    if (tid == 0) out[g] = s2[0] + b3[0];
}

// ===========================================================================
extern "C" void kernel_launch(void* const* d_in, const int* in_sizes, int n_in,
                              void* d_out, int out_size, void* d_ws, size_t ws_size,
                              hipStream_t stream)
{
    const float* link_state = (const float*)d_in[0];
    const int*   gids       = (const int*)d_in[1];
    const int*   first      = (const int*)d_in[2];
    const int*   second     = (const int*)d_in[3];
    const float* Wmsg       = (const float*)d_in[5];
    const float* bmsg       = (const float*)d_in[6];
    const float* gK         = (const float*)d_in[7];
    const float* gU         = (const float*)d_in[8];
    const float* gbias      = (const float*)d_in[9];
    const float* W1         = (const float*)d_in[10];
    const float* b1         = (const float*)d_in[11];
    const float* W2         = (const float*)d_in[12];
    const float* b2         = (const float*)d_in[13];
    const float* W3         = (const float*)d_in[14];
    const float* b3         = (const float*)d_in[15];
    float* out = (float*)d_out;

    // ws layout (16B-aligned segments), ~205 MiB total:
    //   offsets[100004] counts[1e5] cursor[1e5] bsum[128] sfirst[P] ssecond[P]
    //   wt[32768 us] wy[32768 us] wb[196608 us]
    //   hb_hi[E*128 us] hb_lo[E*128 us] agg[E*128 f32] G[E*128 f32] Y2b[E*128 f32]
    int* offsets = (int*)d_ws;
    int* counts  = offsets + 100004;
    int* cursor  = counts + E_NUM;
    int* bsum    = cursor + E_NUM;
    int* sfirst  = bsum + 128;
    int* ssecond = sfirst + P_NUM;
    ushort_t* wt    = (ushort_t*)(ssecond + P_NUM);
    ushort_t* wy    = wt + 32768;
    ushort_t* wb    = wy + 32768;
    ushort_t* hb_hi = wb + 196608;
    ushort_t* hb_lo = hb_hi + (size_t)E_NUM * DIM;
    float*    agg   = (float*)(hb_lo + (size_t)E_NUM * DIM);
    float*    G     = agg + (size_t)E_NUM * DIM;
    float*    Y2b   = G   + (size_t)E_NUM * DIM;

    // ---- one-time prep ----
    hipMemsetAsync(counts, 0, E_NUM * sizeof(int), stream);
    hipMemsetAsync(cursor, 0, E_NUM * sizeof(int), stream);
    hist_kernel<<<P_NUM / 256, 256, 0, stream>>>(second, counts);
    scanA_kernel<<<98, 1024, 0, stream>>>(counts, offsets, bsum);
    scanB_kernel<<<1, 1, 0, stream>>>(bsum, offsets);
    scanC_kernel<<<98, 1024, 0, stream>>>(offsets, bsum);
    fill_kernel<<<P_NUM / 256, 256, 0, stream>>>(first, second, offsets, cursor,
                                                 sfirst, ssecond);
    wsplit_build_kernel<<<32, 256, 0, stream>>>(Wmsg, wt, wy);
    wb_build_kernel<<<96, 256, 0, stream>>>(gK, gU, wb);
    cast_h_kernel<<<(E_NUM * DIM) / 256, 256, 0, stream>>>(link_state, hb_hi, hb_lo);

    // ---- message-passing steps ----
    for (int t = 0; t < T_STEPS; t++) {
        gy_kernel<<<E_NUM / 32, 256, 0, stream>>>(hb_hi, hb_lo, wt, wy, bmsg,
                                                  G, Y2b);
        agg_csr_kernel<<<E_NUM / 32, 256, 0, stream>>>(G, Y2b, offsets, sfirst,
                                                       agg);
        gru_kernel<<<(E_NUM + 63) / 64, 512, 0, stream>>>(agg, hb_hi, hb_lo,
                                                          wb, gbias);
    }

    // ---- pool + readout ----
    float* pooled = agg;  // reuse
    hipMemsetAsync(pooled, 0, (size_t)G_NUM * DIM * sizeof(float), stream);
    pool_kernel<<<(E_NUM * DIM) / 256, 256, 0, stream>>>(hb_hi, hb_lo, gids, pooled);
    readout_kernel<<<G_NUM, 256, 0, stream>>>(pooled, W1, b1, W2, b2, W3, b3, out);
}

// Round 13
// 2660.137 us; speedup vs baseline: 1.8782x; 1.1329x over previous
//
#include <hip/hip_runtime.h>
#include <math.h>

#define DIM 128
#define E_NUM 100000
#define P_NUM 800000
#define G_NUM 1000
#define T_STEPS 8
#define R_UNITS 256

typedef __attribute__((ext_vector_type(8))) short bf16x8;   // 8 bf16 = 4 VGPRs
typedef __attribute__((ext_vector_type(4))) float f32x4;    // 16x16 MFMA acc

typedef unsigned short ushort_t;
typedef unsigned int   uint_t;

__device__ __forceinline__ float selu_f(float x) {
    const float alpha = 1.6732632423543772f;
    const float scale = 1.0507009873554805f;
    return x > 0.f ? scale * x : scale * alpha * expm1f(x);
}

__device__ __forceinline__ ushort_t f2bf(float x) {
    uint_t u = __float_as_uint(x);
    uint_t r = (u + 0x7fffu + ((u >> 16) & 1u)) >> 16;
    return (ushort_t)r;
}
__device__ __forceinline__ float bf2f(ushort_t h) {
    return __uint_as_float(((uint_t)h) << 16);
}

// ===========================================================================
// CSR build (once per launch). Multi-block scan.
// ===========================================================================
__global__ __launch_bounds__(256)
void hist_kernel(const int* __restrict__ second, int* __restrict__ counts)
{
    const int p = blockIdx.x * 256 + threadIdx.x;
    atomicAdd(&counts[second[p]], 1);
}

__global__ __launch_bounds__(1024)
void scanA_kernel(const int* __restrict__ counts, int* __restrict__ offsets,
                  int* __restrict__ bsum)
{
    __shared__ int buf[1024];
    const int i = blockIdx.x * 1024 + threadIdx.x;
    const int v = (i < E_NUM) ? counts[i] : 0;
    buf[threadIdx.x] = v;
    __syncthreads();
    for (int off = 1; off < 1024; off <<= 1) {
        const int t = (threadIdx.x >= off) ? buf[threadIdx.x - off] : 0;
        __syncthreads();
        buf[threadIdx.x] += t;
        __syncthreads();
    }
    if (i < E_NUM) offsets[i] = buf[threadIdx.x] - v;   // block-local exclusive
    if (threadIdx.x == 1023) bsum[blockIdx.x] = buf[1023];
}

__global__ void scanB_kernel(int* __restrict__ bsum, int* __restrict__ offsets)
{
    int acc = 0;
    for (int b = 0; b < 98; b++) { const int t = bsum[b]; bsum[b] = acc; acc += t; }
    offsets[E_NUM] = P_NUM;
}

__global__ __launch_bounds__(1024)
void scanC_kernel(int* __restrict__ offsets, const int* __restrict__ bsum)
{
    const int i = blockIdx.x * 1024 + threadIdx.x;
    if (i < E_NUM) offsets[i] += bsum[blockIdx.x];
}

__global__ __launch_bounds__(256)
void fill_kernel(const int* __restrict__ first, const int* __restrict__ second,
                 const int* __restrict__ offsets, int* __restrict__ cursor,
                 int* __restrict__ sfirst, int* __restrict__ ssecond)
{
    const int p = blockIdx.x * 256 + threadIdx.x;
    const int d = second[p];
    const int pos = atomicAdd(&cursor[d], 1);
    const int idx = offsets[d] + pos;
    sfirst[idx] = first[p];
    ssecond[idx] = d;
}

// ===========================================================================
// One-time prep (unchanged).
// ===========================================================================
__global__ __launch_bounds__(256)
void cast_h_kernel(const float* __restrict__ src,
                   ushort_t* __restrict__ dhi, ushort_t* __restrict__ dlo)
{
    const int idx = blockIdx.x * 256 + threadIdx.x;
    const float x = src[idx];
    const ushort_t hi = f2bf(x);
    dhi[idx] = hi;
    dlo[idx] = f2bf(x - bf2f(hi));
}

__global__ __launch_bounds__(256)
void wsplit_build_kernel(const float* __restrict__ Wmsg,
                         ushort_t* __restrict__ wt, ushort_t* __restrict__ wy)
{
    const int idx  = blockIdx.x * 256 + threadIdx.x;   // 8192 slots (2 halves)
    const int lane = idx & 63;
    const int nt   = (idx >> 6) & 7;
    const int comp = (idx >> 9) & 1;
    const int ks   = (idx >> 10) & 3;
    const int half = idx >> 12;
    const int n    = nt * 16 + (lane & 15);
    const int kb   = ks * 32 + (lane >> 4) * 8 + half * 128;
    ushort_t* dst  = half ? wy : wt;
    const int slot = idx & 4095;
#pragma unroll
    for (int j = 0; j < 8; j++) {
        const float w = Wmsg[(size_t)(kb + j) * DIM + n];
        const ushort_t hi = f2bf(w);
        dst[(size_t)slot * 8 + j] = comp ? f2bf(w - bf2f(hi)) : hi;
    }
}

__global__ __launch_bounds__(256)
void wb_build_kernel(const float* __restrict__ K, const float* __restrict__ U,
                     ushort_t* __restrict__ wb)
{
    const int idx  = blockIdx.x * 256 + threadIdx.x;   // 24576 slots
    const int lane = idx & 63;
    int t = idx >> 6;
    const int nt   = t % 24;  t /= 24;
    const int comp = t & 1;   t >>= 1;
    const int gemm = t & 1;
    const int ks   = t >> 1;
    const float* src = gemm ? U : K;
    const int n  = nt * 16 + (lane & 15);
    const int kb = ks * 32 + (lane >> 4) * 8;
#pragma unroll
    for (int j = 0; j < 8; j++) {
        const float w = src[(size_t)(kb + j) * 384 + n];
        const ushort_t hi = f2bf(w);
        wb[(size_t)idx * 8 + j] = comp ? f2bf(w - bf2f(hi)) : hi;
    }
}

// ===========================================================================
// GY kernel: per step, compute BOTH per-edge GEMMs in one pass:
//   G[e]   = h[e] @ W_top            (f32, no bias)
//   Y2b[e] = h[e] @ W_bot + bmsg     (f32, bias folded)
// ===========================================================================
__global__ __launch_bounds__(256, 4)
void gy_kernel(const ushort_t* __restrict__ hbh, const ushort_t* __restrict__ hbl,
               const ushort_t* __restrict__ wt, const ushort_t* __restrict__ wy,
               const float* __restrict__ bmsg,
               float* __restrict__ G, float* __restrict__ Y2b)
{
    const int tid  = threadIdx.x;
    const int lane = tid & 63;
    const int w    = tid >> 6;
    const int e0   = blockIdx.x * 32;
    const int m16  = lane & 15;
    const int quad = lane >> 4;

    f32x4 acc[2][4] = {};
#pragma unroll
    for (int ks = 0; ks < 4; ks++) {
        const int koff = ks * 32 + quad * 8;
        bf16x8 ah[2], al[2];
#pragma unroll
        for (int rt = 0; rt < 2; rt++) {
            const size_t row = (size_t)(e0 + rt * 16 + m16);
            ah[rt] = *(const bf16x8*)(hbh + row * DIM + koff);
            al[rt] = *(const bf16x8*)(hbl + row * DIM + koff);
        }
#pragma unroll
        for (int ntl = 0; ntl < 4; ntl++) {
            const int ntg = w * 4 + ntl;                    // 0..15
            const ushort_t* wsel = (ntg < 8) ? wt : wy;
            const int nt = ntg & 7;
            const bf16x8 bh = *(const bf16x8*)(wsel + (size_t)(((ks * 2 + 0) * 8 + nt) * 64 + lane) * 8);
            const bf16x8 bl = *(const bf16x8*)(wsel + (size_t)(((ks * 2 + 1) * 8 + nt) * 64 + lane) * 8);
#pragma unroll
            for (int rt = 0; rt < 2; rt++) {
                acc[rt][ntl] = __builtin_amdgcn_mfma_f32_16x16x32_bf16(ah[rt], bh, acc[rt][ntl], 0, 0, 0);
                acc[rt][ntl] = __builtin_amdgcn_mfma_f32_16x16x32_bf16(al[rt], bh, acc[rt][ntl], 0, 0, 0);
                acc[rt][ntl] = __builtin_amdgcn_mfma_f32_16x16x32_bf16(ah[rt], bl, acc[rt][ntl], 0, 0, 0);
            }
        }
    }
    // C layout: col = lane&15, row = quad*4 + reg
#pragma unroll
    for (int ntl = 0; ntl < 4; ntl++) {
        const int ntg = w * 4 + ntl;
        const int c   = (ntg & 7) * 16 + m16;               // 0..127 within half
        const bool isG = (ntg < 8);
        const float bb = isG ? 0.f : bmsg[c];
        float* dst = isG ? G : Y2b;
#pragma unroll
        for (int rt = 0; rt < 2; rt++) {
#pragma unroll
            for (int reg = 0; reg < 4; reg++) {
                const size_t row = (size_t)(e0 + rt * 16 + quad * 4 + reg);
                dst[row * DIM + c] = acc[rt][ntl][reg] + bb;
            }
        }
    }
}

// ===========================================================================
// agg_csr kernel: x[d] = sum_{p in CSR run of d} selu(G[sfirst[p]] + Y2b[d])
// R13: output pre-split bf16 hi/lo (agg_hi/agg_lo) instead of f32 — moves
// the hi/lo decomposition off gru's congested VALU (work conserved, producer
// has spare cycles) and halves agg bytes. Wave per 8 destinations; no LDS,
// no atomics, no memset.
// ===========================================================================
__global__ __launch_bounds__(256)
void agg_csr_kernel(const float* __restrict__ G, const float* __restrict__ Y2b,
                    const int* __restrict__ offsets, const int* __restrict__ sfirst,
                    ushort_t* __restrict__ agg_hi, ushort_t* __restrict__ agg_lo)
{
    const int tid  = threadIdx.x;
    const int lane = tid & 63;
    const int wv   = blockIdx.x * 4 + (tid >> 6);   // global wave id, 0..12499
    const int c2   = lane * 2;

#pragma unroll 1
    for (int i = 0; i < 8; i++) {
        const int d = wv * 8 + i;                   // exact: 12500*8 = 100000
        const int start = offsets[d];
        const int end   = offsets[d + 1];
        const float2 y = *(const float2*)(Y2b + (size_t)d * DIM + c2);
        float a0 = 0.f, a1 = 0.f;
        int p = start;
        for (; p + 4 <= end; p += 4) {
            const int f0 = sfirst[p];
            const int f1 = sfirst[p + 1];
            const int f2 = sfirst[p + 2];
            const int f3 = sfirst[p + 3];
            const float2 g0 = *(const float2*)(G + (size_t)f0 * DIM + c2);
            const float2 g1 = *(const float2*)(G + (size_t)f1 * DIM + c2);
            const float2 g2 = *(const float2*)(G + (size_t)f2 * DIM + c2);
            const float2 g3 = *(const float2*)(G + (size_t)f3 * DIM + c2);
            a0 += selu_f(g0.x + y.x);  a1 += selu_f(g0.y + y.y);
            a0 += selu_f(g1.x + y.x);  a1 += selu_f(g1.y + y.y);
            a0 += selu_f(g2.x + y.x);  a1 += selu_f(g2.y + y.y);
            a0 += selu_f(g3.x + y.x);  a1 += selu_f(g3.y + y.y);
        }
        for (; p < end; p++) {
            const int f = sfirst[p];
            const float2 g = *(const float2*)(G + (size_t)f * DIM + c2);
            a0 += selu_f(g.x + y.x);
            a1 += selu_f(g.y + y.y);
        }
        // split to bf16 hi/lo pairs
        const ushort_t h0 = f2bf(a0);
        const ushort_t h1 = f2bf(a1);
        ushort2 hv, lv;
        hv.x = h0;  hv.y = h1;
        lv.x = f2bf(a0 - bf2f(h0));
        lv.y = f2bf(a1 - bf2f(h1));
        *(ushort2*)(agg_hi + (size_t)d * DIM + c2) = hv;
        *(ushort2*)(agg_lo + (size_t)d * DIM + c2) = lv;
    }
}

// ===========================================================================
// GRU kernel, register-gates. R13: M=32/block (3125 blocks), x pre-split by
// producer -> straight bf16x8 loads, no inline f2bf. acc = 8 f32x4 (32 AGPR);
// (512,4) caps total regs at 128 -> 2 blocks/CU (16 waves, ~50% occupancy).
// Wave w owns nt {w, w+8, w+16}: z/r/h of col c in the same thread.
// ===========================================================================
__global__ __launch_bounds__(512, 4)
void gru_kernel(const ushort_t* __restrict__ xhg, const ushort_t* __restrict__ xlg,
                ushort_t* __restrict__ hbh, ushort_t* __restrict__ hbl,
                const ushort_t* __restrict__ wb, const float* __restrict__ bias)
{
    const int tid  = threadIdx.x;
    const int lane = tid & 63;
    const int w    = tid >> 6;          // 0..7
    const int e0   = blockIdx.x * 32;
    const int m16  = lane & 15;
    const int quad = lane >> 4;

    f32x4 az[2] = {}, ar[2] = {}, ahx[2] = {}, ahh[2] = {};

#define WB(ks_, gm_, cp_, nt_) \
    (*(const bf16x8*)(wb + ((size_t)(((ks_) * 96) + (gm_) * 48 + (cp_) * 24 + (nt_)) * 64 + lane) * 8))

#pragma unroll
    for (int ks = 0; ks < 4; ks++) {
        const int koff = ks * 32 + quad * 8;
        const bf16x8 KzH = WB(ks, 0, 0, w),      KzL = WB(ks, 0, 1, w);
        const bf16x8 UzH = WB(ks, 1, 0, w),      UzL = WB(ks, 1, 1, w);
        const bf16x8 KrH = WB(ks, 0, 0, w + 8),  KrL = WB(ks, 0, 1, w + 8);
        const bf16x8 UrH = WB(ks, 1, 0, w + 8),  UrL = WB(ks, 1, 1, w + 8);
        const bf16x8 KhH = WB(ks, 0, 0, w + 16), KhL = WB(ks, 0, 1, w + 16);
        const bf16x8 UhH = WB(ks, 1, 0, w + 16), UhL = WB(ks, 1, 1, w + 16);
#pragma unroll
        for (int rt = 0; rt < 2; rt++) {
            const size_t row = (size_t)(e0 + rt * 16 + m16);
            const bf16x8 xh = *(const bf16x8*)(xhg + row * DIM + koff);
            const bf16x8 xl = *(const bf16x8*)(xlg + row * DIM + koff);
            const bf16x8 hh = *(const bf16x8*)(hbh + row * DIM + koff);
            const bf16x8 hl = *(const bf16x8*)(hbl + row * DIM + koff);

            az[rt] = __builtin_amdgcn_mfma_f32_16x16x32_bf16(xh, KzH, az[rt], 0, 0, 0);
            az[rt] = __builtin_amdgcn_mfma_f32_16x16x32_bf16(xl, KzH, az[rt], 0, 0, 0);
            az[rt] = __builtin_amdgcn_mfma_f32_16x16x32_bf16(xh, KzL, az[rt], 0, 0, 0);
            az[rt] = __builtin_amdgcn_mfma_f32_16x16x32_bf16(hh, UzH, az[rt], 0, 0, 0);
            az[rt] = __builtin_amdgcn_mfma_f32_16x16x32_bf16(hl, UzH, az[rt], 0, 0, 0);
            az[rt] = __builtin_amdgcn_mfma_f32_16x16x32_bf16(hh, UzL, az[rt], 0, 0, 0);

            ar[rt] = __builtin_amdgcn_mfma_f32_16x16x32_bf16(xh, KrH, ar[rt], 0, 0, 0);
            ar[rt] = __builtin_amdgcn_mfma_f32_16x16x32_bf16(xl, KrH, ar[rt], 0, 0, 0);
            ar[rt] = __builtin_amdgcn_mfma_f32_16x16x32_bf16(xh, KrL, ar[rt], 0, 0, 0);
            ar[rt] = __builtin_amdgcn_mfma_f32_16x16x32_bf16(hh, UrH, ar[rt], 0, 0, 0);
            ar[rt] = __builtin_amdgcn_mfma_f32_16x16x32_bf16(hl, UrH, ar[rt], 0, 0, 0);
            ar[rt] = __builtin_amdgcn_mfma_f32_16x16x32_bf16(hh, UrL, ar[rt], 0, 0, 0);

            ahx[rt] = __builtin_amdgcn_mfma_f32_16x16x32_bf16(xh, KhH, ahx[rt], 0, 0, 0);
            ahx[rt] = __builtin_amdgcn_mfma_f32_16x16x32_bf16(xl, KhH, ahx[rt], 0, 0, 0);
            ahx[rt] = __builtin_amdgcn_mfma_f32_16x16x32_bf16(xh, KhL, ahx[rt], 0, 0, 0);
            ahh[rt] = __builtin_amdgcn_mfma_f32_16x16x32_bf16(hh, UhH, ahh[rt], 0, 0, 0);
            ahh[rt] = __builtin_amdgcn_mfma_f32_16x16x32_bf16(hl, UhH, ahh[rt], 0, 0, 0);
            ahh[rt] = __builtin_amdgcn_mfma_f32_16x16x32_bf16(hh, UhL, ahh[rt], 0, 0, 0);
        }
    }
#undef WB

    __syncthreads();   // all reads of hbh/hbl done before in-place writes

    const int c = w * 16 + m16;
    const float bz  = bias[c] + bias[384 + c];
    const float br  = bias[128 + c] + bias[512 + c];
    const float bxh = bias[256 + c];
    const float brh = bias[640 + c];

#pragma unroll
    for (int rt = 0; rt < 2; rt++) {
#pragma unroll
        for (int reg = 0; reg < 4; reg++) {
            const int row = e0 + rt * 16 + quad * 4 + reg;
            const float z  = 1.f / (1.f + expf(-(az[rt][reg] + bz)));
            const float r  = 1.f / (1.f + expf(-(ar[rt][reg] + br)));
            const float hc = tanhf(ahx[rt][reg] + bxh + r * (ahh[rt][reg] + brh));
            const size_t g = (size_t)row * DIM + c;
            const float hp = bf2f(hbh[g]) + bf2f(hbl[g]);
            const float hn = z * hp + (1.f - z) * hc;
            const ushort_t hi = f2bf(hn);
            hbh[g] = hi;
            hbl[g] = f2bf(hn - bf2f(hi));
        }
    }
}

// ===========================================================================
// Graph pooling + readout
// ===========================================================================
__global__ __launch_bounds__(256)
void pool_kernel(const ushort_t* __restrict__ hbh, const ushort_t* __restrict__ hbl,
                 const int* __restrict__ gid, float* __restrict__ pooled)
{
    const int idx = blockIdx.x * 256 + threadIdx.x;
    const int e = idx >> 7;
    const int n = idx & 127;
    const float hv = bf2f(hbh[idx]) + bf2f(hbl[idx]);
    atomicAdd(pooled + (size_t)gid[e] * DIM + n, hv);
}

__global__ __launch_bounds__(256)
void readout_kernel(const float* __restrict__ pooled,
                    const float* __restrict__ W1, const float* __restrict__ b1,
                    const float* __restrict__ W2, const float* __restrict__ b2,
                    const float* __restrict__ W3, const float* __restrict__ b3,
                    float* __restrict__ out)
{
    __shared__ float sp[DIM];
    __shared__ float s1[R_UNITS];
    __shared__ float s2[R_UNITS];
    const int g = blockIdx.x, tid = threadIdx.x;

    if (tid < DIM) sp[tid] = pooled[(size_t)g * DIM + tid];
    __syncthreads();

    float acc = b1[tid];
    for (int k = 0; k < DIM; k++) acc += sp[k] * W1[(size_t)k * R_UNITS + tid];
    s1[tid] = selu_f(acc);
    __syncthreads();

    acc = b2[tid];
    for (int k = 0; k < R_UNITS; k++) acc += s1[k] * W2[(size_t)k * R_UNITS + tid];
    s2[tid] = selu_f(acc) * W3[tid];
    __syncthreads();

    for (int s = 128; s > 0; s >>= 1) {
        if (tid < s) s2[tid] += s2[tid + s];
        __syncthreads();
    }
    if (tid == 0) out[g] = s2[0] + b3[0];
}

// ===========================================================================
extern "C" void kernel_launch(void* const* d_in, const int* in_sizes, int n_in,
                              void* d_out, int out_size, void* d_ws, size_t ws_size,
                              hipStream_t stream)
{
    const float* link_state = (const float*)d_in[0];
    const int*   gids       = (const int*)d_in[1];
    const int*   first      = (const int*)d_in[2];
    const int*   second     = (const int*)d_in[3];
    const float* Wmsg       = (const float*)d_in[5];
    const float* bmsg       = (const float*)d_in[6];
    const float* gK         = (const float*)d_in[7];
    const float* gU         = (const float*)d_in[8];
    const float* gbias      = (const float*)d_in[9];
    const float* W1         = (const float*)d_in[10];
    const float* b1         = (const float*)d_in[11];
    const float* W2         = (const float*)d_in[12];
    const float* b2         = (const float*)d_in[13];
    const float* W3         = (const float*)d_in[14];
    const float* b3         = (const float*)d_in[15];
    float* out = (float*)d_out;

    // ws layout (16B-aligned segments):
    //   offsets[100004] counts[1e5] cursor[1e5] bsum[128] sfirst[P] ssecond[P]
    //   wt[32768 us] wy[32768 us] wb[196608 us]
    //   hb_hi[E*128 us] hb_lo[E*128 us] agg_hi[E*128 us] agg_lo[E*128 us]
    //   G[E*128 f32] Y2b[E*128 f32]
    int* offsets = (int*)d_ws;
    int* counts  = offsets + 100004;
    int* cursor  = counts + E_NUM;
    int* bsum    = cursor + E_NUM;
    int* sfirst  = bsum + 128;
    int* ssecond = sfirst + P_NUM;
    ushort_t* wt     = (ushort_t*)(ssecond + P_NUM);
    ushort_t* wy     = wt + 32768;
    ushort_t* wb     = wy + 32768;
    ushort_t* hb_hi  = wb + 196608;
    ushort_t* hb_lo  = hb_hi + (size_t)E_NUM * DIM;
    ushort_t* agg_hi = hb_lo + (size_t)E_NUM * DIM;
    ushort_t* agg_lo = agg_hi + (size_t)E_NUM * DIM;
    float*    G      = (float*)(agg_lo + (size_t)E_NUM * DIM);
    float*    Y2b    = G + (size_t)E_NUM * DIM;

    // ---- one-time prep ----
    hipMemsetAsync(counts, 0, E_NUM * sizeof(int), stream);
    hipMemsetAsync(cursor, 0, E_NUM * sizeof(int), stream);
    hist_kernel<<<P_NUM / 256, 256, 0, stream>>>(second, counts);
    scanA_kernel<<<98, 1024, 0, stream>>>(counts, offsets, bsum);
    scanB_kernel<<<1, 1, 0, stream>>>(bsum, offsets);
    scanC_kernel<<<98, 1024, 0, stream>>>(offsets, bsum);
    fill_kernel<<<P_NUM / 256, 256, 0, stream>>>(first, second, offsets, cursor,
                                                 sfirst, ssecond);
    wsplit_build_kernel<<<32, 256, 0, stream>>>(Wmsg, wt, wy);
    wb_build_kernel<<<96, 256, 0, stream>>>(gK, gU, wb);
    cast_h_kernel<<<(E_NUM * DIM) / 256, 256, 0, stream>>>(link_state, hb_hi, hb_lo);

    // ---- message-passing steps ----
    for (int t = 0; t < T_STEPS; t++) {
        gy_kernel<<<E_NUM / 32, 256, 0, stream>>>(hb_hi, hb_lo, wt, wy, bmsg,
                                                  G, Y2b);
        agg_csr_kernel<<<E_NUM / 32, 256, 0, stream>>>(G, Y2b, offsets, sfirst,
                                                       agg_hi, agg_lo);
        gru_kernel<<<E_NUM / 32, 512, 0, stream>>>(agg_hi, agg_lo, hb_hi, hb_lo,
                                                   wb, gbias);
    }

    // ---- pool + readout (G reused as pooled buffer) ----
    float* pooled = G;
    hipMemsetAsync(pooled, 0, (size_t)G_NUM * DIM * sizeof(float), stream);
    pool_kernel<<<(E_NUM * DIM) / 256, 256, 0, stream>>>(hb_hi, hb_lo, gids, pooled);
    readout_kernel<<<G_NUM, 256, 0, stream>>>(pooled, W1, b1, W2, b2, W3, b3, out);
}